// Round 1
// baseline (841.519 us; speedup 1.0000x reference)
//
#include <hip/hip_runtime.h>
#include <hip/hip_bf16.h>
#include <math.h>

typedef unsigned short u16;
typedef __attribute__((ext_vector_type(8))) short s16x8;
typedef __attribute__((ext_vector_type(4))) float f32x4;

#define SCALE 0.083333333333333329f   // 1/sqrt(144)
#define L_SEQ 2048
#define SOFTCAP_INV 0.02f

__device__ __forceinline__ u16 f2bf(float f) {
    unsigned u = __float_as_uint(f);
    unsigned r = 0x7fffu + ((u >> 16) & 1u);
    return (u16)((u + r) >> 16);
}

// ---------------- cast fp32 -> bf16 (vectorized) ----------------
__global__ __launch_bounds__(256) void cast_kernel(const float* __restrict__ in,
                                                   u16* __restrict__ out) {
    size_t i = ((size_t)blockIdx.x * 256 + threadIdx.x) * 4;
    float4 v = *(const float4*)(in + i);
    ushort4 o;
    o.x = f2bf(v.x); o.y = f2bf(v.y); o.z = f2bf(v.z); o.w = f2bf(v.w);
    *(ushort4*)(out + i) = o;
}

// ---------------- rope cos/sin table ----------------
__global__ __launch_bounds__(256) void rope_table_kernel(float* __restrict__ cosT,
                                                         float* __restrict__ sinT) {
    int idx = blockIdx.x * 256 + threadIdx.x;   // L*64
    int i = idx & 63, pos = idx >> 6;
    float inv = __expf(-((float)i / 64.0f) * 9.210340371976184f); // 10000^(-i/64)
    float ang = (float)pos * inv;
    cosT[idx] = cosf(ang);
    sinT[idx] = sinf(ang);
}

// ---------------- rope for Q (32 heads) + scale, fp32 -> bf16 ----------------
__global__ __launch_bounds__(256) void rope_q_kernel(const float* __restrict__ Q32,
                                                     u16* __restrict__ Qb,
                                                     const float* __restrict__ cosT,
                                                     const float* __restrict__ sinT) {
    int idx = blockIdx.x * 256 + threadIdx.x;   // L*32*64
    int i = idx & 63;
    int head = (idx >> 6) & 31;
    int pos = idx >> 11;
    size_t base = (size_t)pos * 4096 + head * 128 + i;
    float t1 = Q32[base], t2 = Q32[base + 64];
    float c = cosT[(pos << 6) + i], s = sinT[(pos << 6) + i];
    Qb[base]      = f2bf((t1 * c - t2 * s) * SCALE);
    Qb[base + 64] = f2bf((t2 * c + t1 * s) * SCALE);
}

// ---------------- rope for K (16 heads), fp32 -> bf16 ----------------
__global__ __launch_bounds__(256) void rope_k_kernel(const float* __restrict__ K32,
                                                     u16* __restrict__ Kb,
                                                     const float* __restrict__ cosT,
                                                     const float* __restrict__ sinT) {
    int idx = blockIdx.x * 256 + threadIdx.x;   // L*16*64
    int i = idx & 63;
    int head = (idx >> 6) & 15;
    int pos = idx >> 10;
    size_t base = (size_t)pos * 2048 + head * 128 + i;
    float t1 = K32[base], t2 = K32[base + 64];
    float c = cosT[(pos << 6) + i], s = sinT[(pos << 6) + i];
    Kb[base]      = f2bf(t1 * c - t2 * s);
    Kb[base + 64] = f2bf(t2 * c + t1 * s);
}

// ---------------- V transpose + cast: [L][2048] f32 -> [2048][L] bf16 ----------------
__global__ __launch_bounds__(256) void vtrans_kernel(const float* __restrict__ V32,
                                                     u16* __restrict__ Vt) {
    __shared__ u16 tile[32][33];
    int bc = (blockIdx.x & 63) << 5;    // col tile of V (c = g*128+d)
    int bl = (blockIdx.x >> 6) << 5;    // row (l) tile
    int x = threadIdx.x & 31, y = threadIdx.x >> 5;
    #pragma unroll
    for (int yy = y; yy < 32; yy += 8)
        tile[yy][x] = f2bf(V32[(size_t)(bl + yy) * 2048 + bc + x]);
    __syncthreads();
    #pragma unroll
    for (int yy = y; yy < 32; yy += 8)
        Vt[(size_t)(bc + yy) * 2048 + bl + x] = tile[x][yy];
}

// ---------------- bf16 GEMM: C(MxN) = A(MxK) * B(NxK)^T, fp32 out ----------------
// m97 structure: 128x128 tile, BK=64, 4 waves, global_load_lds width 16.
__global__ __launch_bounds__(256) void gemm_bt(const u16* __restrict__ A,
                                               const u16* __restrict__ B,
                                               float* __restrict__ C,
                                               int M, int N, int K) {
    __shared__ u16 As[128 * 64];
    __shared__ u16 Bs[128 * 64];
    int nbn = N >> 7;
    int bm = blockIdx.x / nbn, bn = blockIdx.x % nbn;
    int t = threadIdx.x;
    int lane = t & 63, wave = t >> 6;
    int wr = wave >> 1, wc = wave & 1;
    int fr = lane & 15, fq = lane >> 4;
    int srow = t >> 3;            // 0..31
    int scol = (t & 7) * 8;       // element col within BK
    const u16* aS = A + (size_t)(bm * 128 + srow) * K + scol;
    const u16* bS = B + (size_t)(bn * 128 + srow) * K + scol;
    u16* ldsA = &As[wave * 512];
    u16* ldsB = &Bs[wave * 512];

    f32x4 acc[4][4];
    #pragma unroll
    for (int m = 0; m < 4; m++)
        #pragma unroll
        for (int n = 0; n < 4; n++)
            acc[m][n] = (f32x4){0.f, 0.f, 0.f, 0.f};

    for (int k0 = 0; k0 < K; k0 += 64) {
        __syncthreads();
        #pragma unroll
        for (int i = 0; i < 4; i++) {
            __builtin_amdgcn_global_load_lds(
                (const __attribute__((address_space(1))) unsigned int*)(aS + k0 + (size_t)i * 32 * K),
                (__attribute__((address_space(3))) unsigned int*)(ldsA + i * 2048), 16, 0, 0);
            __builtin_amdgcn_global_load_lds(
                (const __attribute__((address_space(1))) unsigned int*)(bS + k0 + (size_t)i * 32 * K),
                (__attribute__((address_space(3))) unsigned int*)(ldsB + i * 2048), 16, 0, 0);
        }
        __syncthreads();
        #pragma unroll
        for (int kk = 0; kk < 2; kk++) {
            s16x8 af[4], bfv[4];
            #pragma unroll
            for (int m = 0; m < 4; m++)
                af[m] = *(const s16x8*)&As[(wr * 64 + m * 16 + fr) * 64 + kk * 32 + fq * 8];
            #pragma unroll
            for (int n = 0; n < 4; n++)
                bfv[n] = *(const s16x8*)&Bs[(wc * 64 + n * 16 + fr) * 64 + kk * 32 + fq * 8];
            #pragma unroll
            for (int m = 0; m < 4; m++)
                #pragma unroll
                for (int n = 0; n < 4; n++)
                    acc[m][n] = __builtin_amdgcn_mfma_f32_16x16x32_bf16(af[m], bfv[n], acc[m][n], 0, 0, 0);
        }
    }
    #pragma unroll
    for (int m = 0; m < 4; m++) {
        int row = bm * 128 + wr * 64 + m * 16 + fq * 4;
        #pragma unroll
        for (int n = 0; n < 4; n++) {
            int col = bn * 128 + wc * 64 + n * 16 + fr;
            #pragma unroll
            for (int r = 0; r < 4; r++)
                C[(size_t)(row + r) * N + col] = acc[m][n][r];
        }
    }
}

// ---------------- flash attention, causal + tanh softcap, GQA 32q/16kv ----------------
// 1 wave per block; block handles 16 q-rows of one q-head.
// Qb: [L][4096] bf16 (rope'd, scaled). Kb: [L][2048] bf16 (rope'd). Vt: [2048][L] bf16.
// Ob: [L][4096] bf16.
__global__ __launch_bounds__(64) void attn_kernel(const u16* __restrict__ Qb,
                                                  const u16* __restrict__ Kb,
                                                  const u16* __restrict__ Vt,
                                                  u16* __restrict__ Ob) {
    __shared__ u16 Pst[1024];   // 16x64 bf16, XOR-swizzled
    int bid = blockIdx.x;
    int hq = bid & 31;
    int rg = 127 - (bid >> 5);       // descending work for load balance
    int g = hq >> 1;
    int lane = threadIdx.x;
    int fr = lane & 15, fq = lane >> 4;
    int qrow0 = rg << 4;

    s16x8 qf[4];
    #pragma unroll
    for (int s = 0; s < 4; s++)
        qf[s] = *(const s16x8*)&Qb[(size_t)(qrow0 + fr) * 4096 + hq * 128 + s * 32 + fq * 8];

    f32x4 o[8];
    #pragma unroll
    for (int c = 0; c < 8; c++) o[c] = (f32x4){0.f, 0.f, 0.f, 0.f};
    float mi[4] = {-INFINITY, -INFINITY, -INFINITY, -INFINITY};
    float li[4] = {0.f, 0.f, 0.f, 0.f};

    int nT = (rg >> 2) + 1;
    for (int kt = 0; kt < nT; kt++) {
        int kv0 = kt << 6;
        f32x4 sf[4];
        #pragma unroll
        for (int j = 0; j < 4; j++) sf[j] = (f32x4){0.f, 0.f, 0.f, 0.f};
        #pragma unroll
        for (int j = 0; j < 4; j++)
            #pragma unroll
            for (int s = 0; s < 4; s++) {
                s16x8 kf = *(const s16x8*)&Kb[(size_t)(kv0 + j * 16 + fr) * 2048 + g * 128 + s * 32 + fq * 8];
                sf[j] = __builtin_amdgcn_mfma_f32_16x16x32_bf16(qf[s], kf, sf[j], 0, 0, 0);
            }
        // softcap + causal mask + row max
        float pmax[4] = {-INFINITY, -INFINITY, -INFINITY, -INFINITY};
        #pragma unroll
        for (int j = 0; j < 4; j++)
            #pragma unroll
            for (int r = 0; r < 4; r++) {
                float sc = 50.f * tanhf(sf[j][r] * SOFTCAP_INV);
                int colk = kv0 + j * 16 + fr;
                int rowq = qrow0 + fq * 4 + r;
                sc = (colk > rowq) ? -INFINITY : sc;
                sf[j][r] = sc;
                pmax[r] = fmaxf(pmax[r], sc);
            }
        #pragma unroll
        for (int d = 1; d < 16; d <<= 1)
            #pragma unroll
            for (int r = 0; r < 4; r++)
                pmax[r] = fmaxf(pmax[r], __shfl_xor(pmax[r], d));
        float al[4], psum[4] = {0.f, 0.f, 0.f, 0.f};
        #pragma unroll
        for (int r = 0; r < 4; r++) {
            float mn = fmaxf(mi[r], pmax[r]);
            al[r] = __expf(mi[r] - mn);
            mi[r] = mn;
        }
        #pragma unroll
        for (int j = 0; j < 4; j++)
            #pragma unroll
            for (int r = 0; r < 4; r++) {
                float p = __expf(sf[j][r] - mi[r]);
                sf[j][r] = p;
                psum[r] += p;
            }
        #pragma unroll
        for (int d = 1; d < 16; d <<= 1)
            #pragma unroll
            for (int r = 0; r < 4; r++)
                psum[r] += __shfl_xor(psum[r], d);
        #pragma unroll
        for (int r = 0; r < 4; r++)
            li[r] = li[r] * al[r] + psum[r];
        #pragma unroll
        for (int c = 0; c < 8; c++)
            #pragma unroll
            for (int r = 0; r < 4; r++)
                o[c][r] *= al[r];
        // P -> LDS (bf16), XOR-swizzled to avoid bank conflicts on b128 reads
        #pragma unroll
        for (int j = 0; j < 4; j++)
            #pragma unroll
            for (int r = 0; r < 4; r++) {
                int row = fq * 4 + r, col = j * 16 + fr;
                int byteoff = (row * 64 + col) * 2;
                byteoff ^= (row & 7) << 4;
                *(u16*)((char*)Pst + byteoff) = f2bf(sf[j][r]);
            }
        __syncthreads();
        // PV
        #pragma unroll
        for (int s = 0; s < 2; s++) {
            int rbyte = (fr * 64 + s * 32 + fq * 8) * 2;
            rbyte ^= (fr & 7) << 4;
            s16x8 pf = *(const s16x8*)((const char*)Pst + rbyte);
            #pragma unroll
            for (int c = 0; c < 8; c++) {
                s16x8 vf = *(const s16x8*)&Vt[(size_t)(g * 128 + c * 16 + fr) * 2048 + kv0 + s * 32 + fq * 8];
                o[c] = __builtin_amdgcn_mfma_f32_16x16x32_bf16(pf, vf, o[c], 0, 0, 0);
            }
        }
        __syncthreads();
    }
    #pragma unroll
    for (int c = 0; c < 8; c++)
        #pragma unroll
        for (int r = 0; r < 4; r++) {
            int rowq = qrow0 + fq * 4 + r;
            Ob[(size_t)rowq * 4096 + hq * 128 + c * 16 + fr] = f2bf(o[c][r] / li[r]);
        }
}

extern "C" void kernel_launch(void* const* d_in, const int* in_sizes, int n_in,
                              void* d_out, int out_size, void* d_ws, size_t ws_size,
                              hipStream_t stream) {
    const float* x  = (const float*)d_in[0];
    // d_in[1] = mask (unused; causal computed directly)
    const float* wq = (const float*)d_in[2];
    const float* wk = (const float*)d_in[3];
    const float* wv = (const float*)d_in[4];
    const float* wo = (const float*)d_in[5];
    float* out = (float*)d_out;

    char* w = (char*)d_ws;
    u16*   xb   = (u16*)(w);                          // 2048*4608 bf16   = 18,874,368 B
    u16*   wb   = (u16*)(w + 18874368);               // weight buf (reused) 37,748,736 B
    float* T32  = (float*)(w + 56623104);             // 2048*4096 f32    = 33,554,432 B
    u16*   Qbuf = (u16*)(w + 90177536);               // 2048*4096 bf16   = 16,777,216 B
    u16*   Kbuf = (u16*)(w + 106954752);              // 2048*2048 bf16   =  8,388,608 B
    u16*   Vt   = (u16*)(w + 115343360);              // 2048*2048 bf16   =  8,388,608 B
    u16*   Ob   = (u16*)(w + 123731968);              // 2048*4096 bf16   = 16,777,216 B
    float* cosT = (float*)(w + 140509184);            // 2048*64 f32
    float* sinT = (float*)(w + 141033472);            // 2048*64 f32

    // rope tables
    rope_table_kernel<<<512, 256, 0, stream>>>(cosT, sinT);
    // cast x
    cast_kernel<<<9216, 256, 0, stream>>>(x, xb);

    // Q = x @ wq^T   (2048 x 4096, K=4608)
    cast_kernel<<<18432, 256, 0, stream>>>(wq, wb);
    gemm_bt<<<512, 256, 0, stream>>>(xb, wb, T32, 2048, 4096, 4608);
    rope_q_kernel<<<16384, 256, 0, stream>>>(T32, Qbuf, cosT, sinT);

    // K = x @ wk^T   (2048 x 2048, K=4608)
    cast_kernel<<<9216, 256, 0, stream>>>(wk, wb);
    gemm_bt<<<256, 256, 0, stream>>>(xb, wb, T32, 2048, 2048, 4608);
    rope_k_kernel<<<8192, 256, 0, stream>>>(T32, Kbuf, cosT, sinT);

    // V = x @ wv^T   (2048 x 2048, K=4608) -> transposed bf16
    cast_kernel<<<9216, 256, 0, stream>>>(wv, wb);
    gemm_bt<<<256, 256, 0, stream>>>(xb, wb, T32, 2048, 2048, 4608);
    vtrans_kernel<<<4096, 256, 0, stream>>>(T32, Vt);

    // attention
    attn_kernel<<<4096, 64, 0, stream>>>(Qbuf, Kbuf, Vt, Ob);

    // out = attn @ wo^T   (2048 x 4608, K=4096)
    cast_kernel<<<18432, 256, 0, stream>>>(wo, wb);
    gemm_bt<<<576, 256, 0, stream>>>(Ob, wb, out, 2048, 4608, 4096);
}

// Round 2
// 684.039 us; speedup vs baseline: 1.2302x; 1.2302x over previous
//
#include <hip/hip_runtime.h>
#include <hip/hip_bf16.h>
#include <math.h>

typedef unsigned short u16;
typedef __attribute__((ext_vector_type(8))) short s16x8;
typedef __attribute__((ext_vector_type(4))) float f32x4;

#define SCALE 0.083333333333333329f   // 1/sqrt(144)
#define L_SEQ 2048
#define SOFTCAP_INV 0.02f

__device__ __forceinline__ u16 f2bf(float f) {
    unsigned u = __float_as_uint(f);
    unsigned r = 0x7fffu + ((u >> 16) & 1u);
    return (u16)((u + r) >> 16);
}

// fast tanh: 1 - 2/(exp(2x)+1)
__device__ __forceinline__ float fast_tanh(float x) {
    float e = __expf(2.0f * x);
    return 1.0f - 2.0f / (e + 1.0f);
}

// ---------------- cast fp32 -> bf16 (vectorized) ----------------
__global__ __launch_bounds__(256) void cast_kernel(const float* __restrict__ in,
                                                   u16* __restrict__ out) {
    size_t i = ((size_t)blockIdx.x * 256 + threadIdx.x) * 4;
    float4 v = *(const float4*)(in + i);
    ushort4 o;
    o.x = f2bf(v.x); o.y = f2bf(v.y); o.z = f2bf(v.z); o.w = f2bf(v.w);
    *(ushort4*)(out + i) = o;
}

// ---------------- rope cos/sin table ----------------
__global__ __launch_bounds__(256) void rope_table_kernel(float* __restrict__ cosT,
                                                         float* __restrict__ sinT) {
    int idx = blockIdx.x * 256 + threadIdx.x;   // L*64
    int i = idx & 63, pos = idx >> 6;
    float inv = __expf(-((float)i / 64.0f) * 9.210340371976184f); // 10000^(-i/64)
    float ang = (float)pos * inv;
    cosT[idx] = cosf(ang);
    sinT[idx] = sinf(ang);
}

// ---------------- rope for Q (32 heads) + scale, fp32 -> bf16 ----------------
__global__ __launch_bounds__(256) void rope_q_kernel(const float* __restrict__ Q32,
                                                     u16* __restrict__ Qb,
                                                     const float* __restrict__ cosT,
                                                     const float* __restrict__ sinT) {
    int idx = blockIdx.x * 256 + threadIdx.x;   // L*32*64
    int i = idx & 63;
    int head = (idx >> 6) & 31;
    int pos = idx >> 11;
    size_t base = (size_t)pos * 4096 + head * 128 + i;
    float t1 = Q32[base], t2 = Q32[base + 64];
    float c = cosT[(pos << 6) + i], s = sinT[(pos << 6) + i];
    Qb[base]      = f2bf((t1 * c - t2 * s) * SCALE);
    Qb[base + 64] = f2bf((t2 * c + t1 * s) * SCALE);
}

// ---------------- rope for K (16 heads), fp32 -> bf16 ----------------
__global__ __launch_bounds__(256) void rope_k_kernel(const float* __restrict__ K32,
                                                     u16* __restrict__ Kb,
                                                     const float* __restrict__ cosT,
                                                     const float* __restrict__ sinT) {
    int idx = blockIdx.x * 256 + threadIdx.x;   // L*16*64
    int i = idx & 63;
    int head = (idx >> 6) & 15;
    int pos = idx >> 10;
    size_t base = (size_t)pos * 2048 + head * 128 + i;
    float t1 = K32[base], t2 = K32[base + 64];
    float c = cosT[(pos << 6) + i], s = sinT[(pos << 6) + i];
    Kb[base]      = f2bf(t1 * c - t2 * s);
    Kb[base + 64] = f2bf(t2 * c + t1 * s);
}

// ---------------- V transpose + cast: [L][2048] f32 -> [2048][L] bf16 ----------------
__global__ __launch_bounds__(256) void vtrans_kernel(const float* __restrict__ V32,
                                                     u16* __restrict__ Vt) {
    __shared__ u16 tile[32][33];
    int bc = (blockIdx.x & 63) << 5;    // col tile of V (c = g*128+d)
    int bl = (blockIdx.x >> 6) << 5;    // row (l) tile
    int x = threadIdx.x & 31, y = threadIdx.x >> 5;
    #pragma unroll
    for (int yy = y; yy < 32; yy += 8)
        tile[yy][x] = f2bf(V32[(size_t)(bl + yy) * 2048 + bc + x]);
    __syncthreads();
    #pragma unroll
    for (int yy = y; yy < 32; yy += 8)
        Vt[(size_t)(bc + yy) * 2048 + bl + x] = tile[x][yy];
}

// ---------------- bf16 GEMM: C(MxN) = A(MxK) * B(NxK)^T, fp32 out ----------------
__global__ __launch_bounds__(256) void gemm_bt(const u16* __restrict__ A,
                                               const u16* __restrict__ B,
                                               float* __restrict__ C,
                                               int M, int N, int K) {
    __shared__ u16 As[128 * 64];
    __shared__ u16 Bs[128 * 64];
    int nbn = N >> 7;
    int bm = blockIdx.x / nbn, bn = blockIdx.x % nbn;
    int t = threadIdx.x;
    int lane = t & 63, wave = t >> 6;
    int wr = wave >> 1, wc = wave & 1;
    int fr = lane & 15, fq = lane >> 4;
    int srow = t >> 3;            // 0..31
    int scol = (t & 7) * 8;       // element col within BK
    const u16* aS = A + (size_t)(bm * 128 + srow) * K + scol;
    const u16* bS = B + (size_t)(bn * 128 + srow) * K + scol;
    u16* ldsA = &As[wave * 512];
    u16* ldsB = &Bs[wave * 512];

    f32x4 acc[4][4];
    #pragma unroll
    for (int m = 0; m < 4; m++)
        #pragma unroll
        for (int n = 0; n < 4; n++)
            acc[m][n] = (f32x4){0.f, 0.f, 0.f, 0.f};

    for (int k0 = 0; k0 < K; k0 += 64) {
        __syncthreads();
        #pragma unroll
        for (int i = 0; i < 4; i++) {
            __builtin_amdgcn_global_load_lds(
                (const __attribute__((address_space(1))) unsigned int*)(aS + k0 + (size_t)i * 32 * K),
                (__attribute__((address_space(3))) unsigned int*)(ldsA + i * 2048), 16, 0, 0);
            __builtin_amdgcn_global_load_lds(
                (const __attribute__((address_space(1))) unsigned int*)(bS + k0 + (size_t)i * 32 * K),
                (__attribute__((address_space(3))) unsigned int*)(ldsB + i * 2048), 16, 0, 0);
        }
        __syncthreads();
        #pragma unroll
        for (int kk = 0; kk < 2; kk++) {
            s16x8 af[4], bfv[4];
            #pragma unroll
            for (int m = 0; m < 4; m++)
                af[m] = *(const s16x8*)&As[(wr * 64 + m * 16 + fr) * 64 + kk * 32 + fq * 8];
            #pragma unroll
            for (int n = 0; n < 4; n++)
                bfv[n] = *(const s16x8*)&Bs[(wc * 64 + n * 16 + fr) * 64 + kk * 32 + fq * 8];
            #pragma unroll
            for (int m = 0; m < 4; m++)
                #pragma unroll
                for (int n = 0; n < 4; n++)
                    acc[m][n] = __builtin_amdgcn_mfma_f32_16x16x32_bf16(af[m], bfv[n], acc[m][n], 0, 0, 0);
        }
    }
    #pragma unroll
    for (int m = 0; m < 4; m++) {
        int row = bm * 128 + wr * 64 + m * 16 + fq * 4;
        #pragma unroll
        for (int n = 0; n < 4; n++) {
            int col = bn * 128 + wc * 64 + n * 16 + fr;
            #pragma unroll
            for (int r = 0; r < 4; r++)
                C[(size_t)(row + r) * N + col] = acc[m][n][r];
        }
    }
}

// ---------------- flash attention v2: 4 waves/block, LDS-staged K/V ----------------
// Block: 256 threads = 4 waves; block covers 64 q-rows of one head (wave w: rows
// qb*64 + w*16 .. +15). K tile (64kv x 128d) and V^T tile (128d x 64kv) staged in
// LDS via global_load_lds with pre-swizzled source (byte ^= (row&7)<<4).
__global__ __launch_bounds__(256) void attn_kernel(const u16* __restrict__ Qb,
                                                   const u16* __restrict__ Kb,
                                                   const u16* __restrict__ Vt,
                                                   u16* __restrict__ Ob) {
    __shared__ u16 Ks[64 * 128];    // 16 KB, rows of 256B, swizzled
    __shared__ u16 Vs[128 * 64];    // 16 KB, rows of 128B, swizzled
    __shared__ u16 Pst[4 * 1024];   // 2 KB per wave, 16x64 bf16, swizzled

    int bid = blockIdx.x;
    int hq = bid & 31;
    int qb = 31 - (bid >> 5);       // heavy blocks first
    int g = hq >> 1;
    int t = threadIdx.x;
    int lane = t & 63, wave = t >> 6;
    int fr = lane & 15, fq = lane >> 4;
    int sw = (fr & 7) << 4;         // fragment-read swizzle (row&7 == fr&7)
    int qrow0 = qb * 64 + wave * 16;
    u16* Pw = &Pst[wave * 1024];

    // Q fragments (16 rows x 128d per wave)
    s16x8 qf[4];
    #pragma unroll
    for (int s = 0; s < 4; s++)
        qf[s] = *(const s16x8*)&Qb[(size_t)(qrow0 + fr) * 4096 + hq * 128 + s * 32 + fq * 8];

    f32x4 o[8];
    #pragma unroll
    for (int c = 0; c < 8; c++) o[c] = (f32x4){0.f, 0.f, 0.f, 0.f};
    float mi[4] = {-INFINITY, -INFINITY, -INFINITY, -INFINITY};
    float li[4] = {0.f, 0.f, 0.f, 0.f};

    // precompute staging addresses (row/col within tile)
    int w4 = wave * 4;
    int nT = qb + 1;
    for (int kt = 0; kt < nT; kt++) {
        int kv0 = kt << 6;
        __syncthreads();   // previous compute done reading Ks/Vs
        #pragma unroll
        for (int i = 0; i < 4; i++) {
            int li_ = w4 + i;
            // K tile: row = kv index 0..63, 256B rows
            int rk = li_ * 4 + (lane >> 4);
            int cbk = ((lane & 15) * 16) ^ ((rk & 7) << 4);
            const u16* srcK = Kb + (size_t)(kv0 + rk) * 2048 + g * 128 + (cbk >> 1);
            __builtin_amdgcn_global_load_lds(
                (const __attribute__((address_space(1))) unsigned int*)srcK,
                (__attribute__((address_space(3))) unsigned int*)(Ks + li_ * 512), 16, 0, 0);
            // V tile: row = d index 0..127, 128B rows
            int rv = li_ * 8 + (lane >> 3);
            int cbv = ((lane & 7) * 16) ^ ((rv & 7) << 4);
            const u16* srcV = Vt + (size_t)(g * 128 + rv) * 2048 + kv0 + (cbv >> 1);
            __builtin_amdgcn_global_load_lds(
                (const __attribute__((address_space(1))) unsigned int*)srcV,
                (__attribute__((address_space(3))) unsigned int*)(Vs + li_ * 512), 16, 0, 0);
        }
        __syncthreads();   // staging complete

        if (kv0 <= qrow0 + 15) {    // wave has unmasked work in this tile
            // ---- QK^T ----
            f32x4 sf[4];
            #pragma unroll
            for (int j = 0; j < 4; j++) sf[j] = (f32x4){0.f, 0.f, 0.f, 0.f};
            #pragma unroll
            for (int j = 0; j < 4; j++)
                #pragma unroll
                for (int s = 0; s < 4; s++) {
                    s16x8 kf = *(const s16x8*)&Ks[(j * 16 + fr) * 128 + (((s * 64 + fq * 16) ^ sw) >> 1)];
                    sf[j] = __builtin_amdgcn_mfma_f32_16x16x32_bf16(qf[s], kf, sf[j], 0, 0, 0);
                }
            // ---- softcap + causal mask + row max ----
            float pmax[4] = {-INFINITY, -INFINITY, -INFINITY, -INFINITY};
            #pragma unroll
            for (int j = 0; j < 4; j++)
                #pragma unroll
                for (int r = 0; r < 4; r++) {
                    float sc = 50.f * fast_tanh(sf[j][r] * SOFTCAP_INV);
                    int colk = kv0 + j * 16 + fr;
                    int rowq = qrow0 + fq * 4 + r;
                    sc = (colk > rowq) ? -INFINITY : sc;
                    sf[j][r] = sc;
                    pmax[r] = fmaxf(pmax[r], sc);
                }
            #pragma unroll
            for (int d = 1; d < 16; d <<= 1)
                #pragma unroll
                for (int r = 0; r < 4; r++)
                    pmax[r] = fmaxf(pmax[r], __shfl_xor(pmax[r], d));
            float al[4], psum[4] = {0.f, 0.f, 0.f, 0.f};
            #pragma unroll
            for (int r = 0; r < 4; r++) {
                float mn = fmaxf(mi[r], pmax[r]);
                al[r] = __expf(mi[r] - mn);
                mi[r] = mn;
            }
            #pragma unroll
            for (int j = 0; j < 4; j++)
                #pragma unroll
                for (int r = 0; r < 4; r++) {
                    float p = __expf(sf[j][r] - mi[r]);
                    sf[j][r] = p;
                    psum[r] += p;
                }
            #pragma unroll
            for (int d = 1; d < 16; d <<= 1)
                #pragma unroll
                for (int r = 0; r < 4; r++)
                    psum[r] += __shfl_xor(psum[r], d);
            #pragma unroll
            for (int r = 0; r < 4; r++)
                li[r] = li[r] * al[r] + psum[r];
            #pragma unroll
            for (int c = 0; c < 8; c++)
                #pragma unroll
                for (int r = 0; r < 4; r++)
                    o[c][r] *= al[r];
            // ---- P -> LDS (bf16, swizzled, per-wave buffer) ----
            #pragma unroll
            for (int j = 0; j < 4; j++)
                #pragma unroll
                for (int r = 0; r < 4; r++) {
                    int row = fq * 4 + r, col = j * 16 + fr;
                    int byteoff = (row * 128 + col * 2) ^ ((row & 7) << 4);
                    *(u16*)((char*)Pw + byteoff) = f2bf(sf[j][r]);
                }
            // ---- PV ----
            #pragma unroll
            for (int s = 0; s < 2; s++) {
                int rbyte = (fr * 128 + s * 64 + fq * 16) ^ sw;
                s16x8 pf = *(const s16x8*)((const char*)Pw + rbyte);
                #pragma unroll
                for (int c = 0; c < 8; c++) {
                    s16x8 vf = *(const s16x8*)&Vs[(c * 16 + fr) * 64 + (((s * 64 + fq * 16) ^ sw) >> 1)];
                    o[c] = __builtin_amdgcn_mfma_f32_16x16x32_bf16(pf, vf, o[c], 0, 0, 0);
                }
            }
        }
    }
    #pragma unroll
    for (int c = 0; c < 8; c++)
        #pragma unroll
        for (int r = 0; r < 4; r++) {
            int rowq = qrow0 + fq * 4 + r;
            Ob[(size_t)rowq * 4096 + hq * 128 + c * 16 + fr] = f2bf(o[c][r] / li[r]);
        }
}

extern "C" void kernel_launch(void* const* d_in, const int* in_sizes, int n_in,
                              void* d_out, int out_size, void* d_ws, size_t ws_size,
                              hipStream_t stream) {
    const float* x  = (const float*)d_in[0];
    // d_in[1] = mask (unused; causal computed directly)
    const float* wq = (const float*)d_in[2];
    const float* wk = (const float*)d_in[3];
    const float* wv = (const float*)d_in[4];
    const float* wo = (const float*)d_in[5];
    float* out = (float*)d_out;

    char* w = (char*)d_ws;
    u16*   xb   = (u16*)(w);                          // 2048*4608 bf16   = 18,874,368 B
    u16*   wb   = (u16*)(w + 18874368);               // weight buf (reused) 37,748,736 B
    float* T32  = (float*)(w + 56623104);             // 2048*4096 f32    = 33,554,432 B
    u16*   Qbuf = (u16*)(w + 90177536);               // 2048*4096 bf16   = 16,777,216 B
    u16*   Kbuf = (u16*)(w + 106954752);              // 2048*2048 bf16   =  8,388,608 B
    u16*   Vt   = (u16*)(w + 115343360);              // 2048*2048 bf16   =  8,388,608 B
    u16*   Ob   = (u16*)(w + 123731968);              // 2048*4096 bf16   = 16,777,216 B
    float* cosT = (float*)(w + 140509184);            // 2048*64 f32
    float* sinT = (float*)(w + 141033472);            // 2048*64 f32

    // rope tables
    rope_table_kernel<<<512, 256, 0, stream>>>(cosT, sinT);
    // cast x
    cast_kernel<<<9216, 256, 0, stream>>>(x, xb);

    // Q = x @ wq^T   (2048 x 4096, K=4608)
    cast_kernel<<<18432, 256, 0, stream>>>(wq, wb);
    gemm_bt<<<512, 256, 0, stream>>>(xb, wb, T32, 2048, 4096, 4608);
    rope_q_kernel<<<16384, 256, 0, stream>>>(T32, Qbuf, cosT, sinT);

    // K = x @ wk^T   (2048 x 2048, K=4608)
    cast_kernel<<<9216, 256, 0, stream>>>(wk, wb);
    gemm_bt<<<256, 256, 0, stream>>>(xb, wb, T32, 2048, 2048, 4608);
    rope_k_kernel<<<8192, 256, 0, stream>>>(T32, Kbuf, cosT, sinT);

    // V = x @ wv^T   (2048 x 2048, K=4608) -> transposed bf16
    cast_kernel<<<9216, 256, 0, stream>>>(wv, wb);
    gemm_bt<<<256, 256, 0, stream>>>(xb, wb, T32, 2048, 2048, 4608);
    vtrans_kernel<<<4096, 256, 0, stream>>>(T32, Vt);

    // attention
    attn_kernel<<<1024, 256, 0, stream>>>(Qbuf, Kbuf, Vt, Ob);

    // out = attn @ wo^T   (2048 x 4608, K=4096)
    cast_kernel<<<18432, 256, 0, stream>>>(wo, wb);
    gemm_bt<<<576, 256, 0, stream>>>(Ob, wb, out, 2048, 4608, 4096);
}

// Round 3
// 651.143 us; speedup vs baseline: 1.2924x; 1.0505x over previous
//
#include <hip/hip_runtime.h>
#include <hip/hip_bf16.h>
#include <math.h>

typedef unsigned short u16;
typedef __attribute__((ext_vector_type(8))) short s16x8;
typedef __attribute__((ext_vector_type(4))) float f32x4;

#define SCALE 0.083333333333333329f   // 1/sqrt(144)
#define SOFTCAP_INV 0.02f

__device__ __forceinline__ u16 f2bf(float f) {
    unsigned u = __float_as_uint(f);
    unsigned r = 0x7fffu + ((u >> 16) & 1u);
    return (u16)((u + r) >> 16);
}

__device__ __forceinline__ float fast_tanh(float x) {
    float e = __expf(2.0f * x);
    return 1.0f - 2.0f / (e + 1.0f);
}

// ---------------- cast fp32 -> bf16 (vectorized) ----------------
__global__ __launch_bounds__(256) void cast_kernel(const float* __restrict__ in,
                                                   u16* __restrict__ out) {
    size_t i = ((size_t)blockIdx.x * 256 + threadIdx.x) * 4;
    float4 v = *(const float4*)(in + i);
    ushort4 o;
    o.x = f2bf(v.x); o.y = f2bf(v.y); o.z = f2bf(v.z); o.w = f2bf(v.w);
    *(ushort4*)(out + i) = o;
}

// ---------------- rope cos/sin table ----------------
__global__ __launch_bounds__(256) void rope_table_kernel(float* __restrict__ cosT,
                                                         float* __restrict__ sinT) {
    int idx = blockIdx.x * 256 + threadIdx.x;   // L*64
    int i = idx & 63, pos = idx >> 6;
    float inv = __expf(-((float)i / 64.0f) * 9.210340371976184f); // 10000^(-i/64)
    float ang = (float)pos * inv;
    cosT[idx] = cosf(ang);
    sinT[idx] = sinf(ang);
}

// ---------------- rope for Q from fused T32 [2048][8192], cols 0..4095 ----------------
__global__ __launch_bounds__(256) void rope_q_kernel(const float* __restrict__ T32,
                                                     u16* __restrict__ Qb,
                                                     const float* __restrict__ cosT,
                                                     const float* __restrict__ sinT) {
    int idx = blockIdx.x * 256 + threadIdx.x;   // L*32*64
    int i = idx & 63;
    int head = (idx >> 6) & 31;
    int pos = idx >> 11;
    size_t rbase = (size_t)pos * 8192 + head * 128 + i;
    float t1 = T32[rbase], t2 = T32[rbase + 64];
    float c = cosT[(pos << 6) + i], s = sinT[(pos << 6) + i];
    size_t wbase = (size_t)pos * 4096 + head * 128 + i;
    Qb[wbase]      = f2bf((t1 * c - t2 * s) * SCALE);
    Qb[wbase + 64] = f2bf((t2 * c + t1 * s) * SCALE);
}

// ---------------- rope for K from fused T32, cols 4096..6143 ----------------
__global__ __launch_bounds__(256) void rope_k_kernel(const float* __restrict__ T32,
                                                     u16* __restrict__ Kb,
                                                     const float* __restrict__ cosT,
                                                     const float* __restrict__ sinT) {
    int idx = blockIdx.x * 256 + threadIdx.x;   // L*16*64
    int i = idx & 63;
    int head = (idx >> 6) & 15;
    int pos = idx >> 10;
    size_t rbase = (size_t)pos * 8192 + 4096 + head * 128 + i;
    float t1 = T32[rbase], t2 = T32[rbase + 64];
    float c = cosT[(pos << 6) + i], s = sinT[(pos << 6) + i];
    size_t wbase = (size_t)pos * 2048 + head * 128 + i;
    Kb[wbase]      = f2bf(t1 * c - t2 * s);
    Kb[wbase + 64] = f2bf(t2 * c + t1 * s);
}

// ---------------- V transpose + cast from fused T32, cols 6144..8191 ----------------
__global__ __launch_bounds__(256) void vtrans_kernel(const float* __restrict__ T32,
                                                     u16* __restrict__ Vt) {
    __shared__ u16 tile[32][33];
    int bc = (blockIdx.x & 63) << 5;    // col within V block (0..2047)
    int bl = (blockIdx.x >> 6) << 5;    // row (l) tile
    int x = threadIdx.x & 31, y = threadIdx.x >> 5;
    #pragma unroll
    for (int yy = y; yy < 32; yy += 8)
        tile[yy][x] = f2bf(T32[(size_t)(bl + yy) * 8192 + 6144 + bc + x]);
    __syncthreads();
    #pragma unroll
    for (int yy = y; yy < 32; yy += 8)
        Vt[(size_t)(bc + yy) * 2048 + bl + x] = tile[x][yy];
}

// ---------------- bf16 GEMM: C(MxN) = A(MxK) * B(NxK)^T, fp32 out ----------------
// m97 structure: 128x128 tile, BK=64, 4 waves, global_load_lds width 16. XCD swizzle.
__global__ __launch_bounds__(256) void gemm_bt(const u16* __restrict__ A,
                                               const u16* __restrict__ B,
                                               float* __restrict__ C,
                                               int M, int N, int K) {
    __shared__ u16 As[128 * 64];
    __shared__ u16 Bs[128 * 64];
    int nbn = N >> 7;
    int bid = blockIdx.x;
    int nwg = gridDim.x;
    if ((nwg & 7) == 0) {
        int cpx = nwg >> 3;
        bid = (bid & 7) * cpx + (bid >> 3);
    }
    int bm = bid / nbn, bn = bid % nbn;
    int t = threadIdx.x;
    int lane = t & 63, wave = t >> 6;
    int wr = wave >> 1, wc = wave & 1;
    int fr = lane & 15, fq = lane >> 4;
    int srow = t >> 3;            // 0..31
    int scol = (t & 7) * 8;       // element col within BK
    const u16* aS = A + (size_t)(bm * 128 + srow) * K + scol;
    const u16* bS = B + (size_t)(bn * 128 + srow) * K + scol;
    u16* ldsA = &As[wave * 512];
    u16* ldsB = &Bs[wave * 512];

    f32x4 acc[4][4];
    #pragma unroll
    for (int m = 0; m < 4; m++)
        #pragma unroll
        for (int n = 0; n < 4; n++)
            acc[m][n] = (f32x4){0.f, 0.f, 0.f, 0.f};

    for (int k0 = 0; k0 < K; k0 += 64) {
        __syncthreads();
        #pragma unroll
        for (int i = 0; i < 4; i++) {
            __builtin_amdgcn_global_load_lds(
                (const __attribute__((address_space(1))) unsigned int*)(aS + k0 + (size_t)i * 32 * K),
                (__attribute__((address_space(3))) unsigned int*)(ldsA + i * 2048), 16, 0, 0);
            __builtin_amdgcn_global_load_lds(
                (const __attribute__((address_space(1))) unsigned int*)(bS + k0 + (size_t)i * 32 * K),
                (__attribute__((address_space(3))) unsigned int*)(ldsB + i * 2048), 16, 0, 0);
        }
        __syncthreads();
        #pragma unroll
        for (int kk = 0; kk < 2; kk++) {
            s16x8 af[4], bfv[4];
            #pragma unroll
            for (int m = 0; m < 4; m++)
                af[m] = *(const s16x8*)&As[(wr * 64 + m * 16 + fr) * 64 + kk * 32 + fq * 8];
            #pragma unroll
            for (int n = 0; n < 4; n++)
                bfv[n] = *(const s16x8*)&Bs[(wc * 64 + n * 16 + fr) * 64 + kk * 32 + fq * 8];
            #pragma unroll
            for (int m = 0; m < 4; m++)
                #pragma unroll
                for (int n = 0; n < 4; n++)
                    acc[m][n] = __builtin_amdgcn_mfma_f32_16x16x32_bf16(af[m], bfv[n], acc[m][n], 0, 0, 0);
        }
    }
    #pragma unroll
    for (int m = 0; m < 4; m++) {
        int row = bm * 128 + wr * 64 + m * 16 + fq * 4;
        #pragma unroll
        for (int n = 0; n < 4; n++) {
            int col = bn * 128 + wc * 64 + n * 16 + fr;
            #pragma unroll
            for (int r = 0; r < 4; r++)
                C[(size_t)(row + r) * N + col] = acc[m][n][r];
        }
    }
}

// ---------------- split-K=2 bf16 GEMM with atomic f32 accumulate into C ----------------
// grid = 2 * (M/128)*(N/128); C must be zeroed before launch.
__global__ __launch_bounds__(256) void gemm_bt_sk2(const u16* __restrict__ A,
                                                   const u16* __restrict__ B,
                                                   float* __restrict__ C,
                                                   int M, int N, int K) {
    __shared__ u16 As[128 * 64];
    __shared__ u16 Bs[128 * 64];
    int nbn = N >> 7;
    int bid = blockIdx.x;
    int nwg = gridDim.x;
    if ((nwg & 7) == 0) {
        int cpx = nwg >> 3;
        bid = (bid & 7) * cpx + (bid >> 3);
    }
    int half = bid & 1;
    int tile = bid >> 1;
    int bm = tile / nbn, bn = tile % nbn;
    int kbeg = half * (K >> 1);
    int kend = kbeg + (K >> 1);
    int t = threadIdx.x;
    int lane = t & 63, wave = t >> 6;
    int wr = wave >> 1, wc = wave & 1;
    int fr = lane & 15, fq = lane >> 4;
    int srow = t >> 3;
    int scol = (t & 7) * 8;
    const u16* aS = A + (size_t)(bm * 128 + srow) * K + scol;
    const u16* bS = B + (size_t)(bn * 128 + srow) * K + scol;
    u16* ldsA = &As[wave * 512];
    u16* ldsB = &Bs[wave * 512];

    f32x4 acc[4][4];
    #pragma unroll
    for (int m = 0; m < 4; m++)
        #pragma unroll
        for (int n = 0; n < 4; n++)
            acc[m][n] = (f32x4){0.f, 0.f, 0.f, 0.f};

    for (int k0 = kbeg; k0 < kend; k0 += 64) {
        __syncthreads();
        #pragma unroll
        for (int i = 0; i < 4; i++) {
            __builtin_amdgcn_global_load_lds(
                (const __attribute__((address_space(1))) unsigned int*)(aS + k0 + (size_t)i * 32 * K),
                (__attribute__((address_space(3))) unsigned int*)(ldsA + i * 2048), 16, 0, 0);
            __builtin_amdgcn_global_load_lds(
                (const __attribute__((address_space(1))) unsigned int*)(bS + k0 + (size_t)i * 32 * K),
                (__attribute__((address_space(3))) unsigned int*)(ldsB + i * 2048), 16, 0, 0);
        }
        __syncthreads();
        #pragma unroll
        for (int kk = 0; kk < 2; kk++) {
            s16x8 af[4], bfv[4];
            #pragma unroll
            for (int m = 0; m < 4; m++)
                af[m] = *(const s16x8*)&As[(wr * 64 + m * 16 + fr) * 64 + kk * 32 + fq * 8];
            #pragma unroll
            for (int n = 0; n < 4; n++)
                bfv[n] = *(const s16x8*)&Bs[(wc * 64 + n * 16 + fr) * 64 + kk * 32 + fq * 8];
            #pragma unroll
            for (int m = 0; m < 4; m++)
                #pragma unroll
                for (int n = 0; n < 4; n++)
                    acc[m][n] = __builtin_amdgcn_mfma_f32_16x16x32_bf16(af[m], bfv[n], acc[m][n], 0, 0, 0);
        }
    }
    #pragma unroll
    for (int m = 0; m < 4; m++) {
        int row = bm * 128 + wr * 64 + m * 16 + fq * 4;
        #pragma unroll
        for (int n = 0; n < 4; n++) {
            int col = bn * 128 + wc * 64 + n * 16 + fr;
            #pragma unroll
            for (int r = 0; r < 4; r++)
                atomicAdd(&C[(size_t)(row + r) * N + col], acc[m][n][r]);
        }
    }
}

// ---------------- flash attention: 4 waves/block, LDS-staged K/V ----------------
__global__ __launch_bounds__(256) void attn_kernel(const u16* __restrict__ Qb,
                                                   const u16* __restrict__ Kb,
                                                   const u16* __restrict__ Vt,
                                                   u16* __restrict__ Ob) {
    __shared__ u16 Ks[64 * 128];    // 16 KB, swizzled
    __shared__ u16 Vs[128 * 64];    // 16 KB, swizzled
    __shared__ u16 Pst[4 * 1024];   // 2 KB per wave

    int bid = blockIdx.x;
    int hq = bid & 31;
    int qb = 31 - (bid >> 5);       // heavy blocks first
    int g = hq >> 1;
    int t = threadIdx.x;
    int lane = t & 63, wave = t >> 6;
    int fr = lane & 15, fq = lane >> 4;
    int sw = (fr & 7) << 4;
    int qrow0 = qb * 64 + wave * 16;
    u16* Pw = &Pst[wave * 1024];

    s16x8 qf[4];
    #pragma unroll
    for (int s = 0; s < 4; s++)
        qf[s] = *(const s16x8*)&Qb[(size_t)(qrow0 + fr) * 4096 + hq * 128 + s * 32 + fq * 8];

    f32x4 o[8];
    #pragma unroll
    for (int c = 0; c < 8; c++) o[c] = (f32x4){0.f, 0.f, 0.f, 0.f};
    float mi[4] = {-INFINITY, -INFINITY, -INFINITY, -INFINITY};
    float li[4] = {0.f, 0.f, 0.f, 0.f};

    int w4 = wave * 4;
    int nT = qb + 1;
    for (int kt = 0; kt < nT; kt++) {
        int kv0 = kt << 6;
        __syncthreads();
        #pragma unroll
        for (int i = 0; i < 4; i++) {
            int li_ = w4 + i;
            int rk = li_ * 4 + (lane >> 4);
            int cbk = ((lane & 15) * 16) ^ ((rk & 7) << 4);
            const u16* srcK = Kb + (size_t)(kv0 + rk) * 2048 + g * 128 + (cbk >> 1);
            __builtin_amdgcn_global_load_lds(
                (const __attribute__((address_space(1))) unsigned int*)srcK,
                (__attribute__((address_space(3))) unsigned int*)(Ks + li_ * 512), 16, 0, 0);
            int rv = li_ * 8 + (lane >> 3);
            int cbv = ((lane & 7) * 16) ^ ((rv & 7) << 4);
            const u16* srcV = Vt + (size_t)(g * 128 + rv) * 2048 + kv0 + (cbv >> 1);
            __builtin_amdgcn_global_load_lds(
                (const __attribute__((address_space(1))) unsigned int*)srcV,
                (__attribute__((address_space(3))) unsigned int*)(Vs + li_ * 512), 16, 0, 0);
        }
        __syncthreads();

        if (kv0 <= qrow0 + 15) {
            f32x4 sf[4];
            #pragma unroll
            for (int j = 0; j < 4; j++) sf[j] = (f32x4){0.f, 0.f, 0.f, 0.f};
            #pragma unroll
            for (int j = 0; j < 4; j++)
                #pragma unroll
                for (int s = 0; s < 4; s++) {
                    s16x8 kf = *(const s16x8*)&Ks[(j * 16 + fr) * 128 + (((s * 64 + fq * 16) ^ sw) >> 1)];
                    sf[j] = __builtin_amdgcn_mfma_f32_16x16x32_bf16(qf[s], kf, sf[j], 0, 0, 0);
                }
            float pmax[4] = {-INFINITY, -INFINITY, -INFINITY, -INFINITY};
            #pragma unroll
            for (int j = 0; j < 4; j++)
                #pragma unroll
                for (int r = 0; r < 4; r++) {
                    float sc = 50.f * fast_tanh(sf[j][r] * SOFTCAP_INV);
                    int colk = kv0 + j * 16 + fr;
                    int rowq = qrow0 + fq * 4 + r;
                    sc = (colk > rowq) ? -INFINITY : sc;
                    sf[j][r] = sc;
                    pmax[r] = fmaxf(pmax[r], sc);
                }
            #pragma unroll
            for (int d = 1; d < 16; d <<= 1)
                #pragma unroll
                for (int r = 0; r < 4; r++)
                    pmax[r] = fmaxf(pmax[r], __shfl_xor(pmax[r], d));
            float al[4], psum[4] = {0.f, 0.f, 0.f, 0.f};
            #pragma unroll
            for (int r = 0; r < 4; r++) {
                float mn = fmaxf(mi[r], pmax[r]);
                al[r] = __expf(mi[r] - mn);
                mi[r] = mn;
            }
            #pragma unroll
            for (int j = 0; j < 4; j++)
                #pragma unroll
                for (int r = 0; r < 4; r++) {
                    float p = __expf(sf[j][r] - mi[r]);
                    sf[j][r] = p;
                    psum[r] += p;
                }
            #pragma unroll
            for (int d = 1; d < 16; d <<= 1)
                #pragma unroll
                for (int r = 0; r < 4; r++)
                    psum[r] += __shfl_xor(psum[r], d);
            #pragma unroll
            for (int r = 0; r < 4; r++)
                li[r] = li[r] * al[r] + psum[r];
            #pragma unroll
            for (int c = 0; c < 8; c++)
                #pragma unroll
                for (int r = 0; r < 4; r++)
                    o[c][r] *= al[r];
            #pragma unroll
            for (int j = 0; j < 4; j++)
                #pragma unroll
                for (int r = 0; r < 4; r++) {
                    int row = fq * 4 + r, col = j * 16 + fr;
                    int byteoff = (row * 128 + col * 2) ^ ((row & 7) << 4);
                    *(u16*)((char*)Pw + byteoff) = f2bf(sf[j][r]);
                }
            #pragma unroll
            for (int s = 0; s < 2; s++) {
                int rbyte = (fr * 128 + s * 64 + fq * 16) ^ sw;
                s16x8 pf = *(const s16x8*)((const char*)Pw + rbyte);
                #pragma unroll
                for (int c = 0; c < 8; c++) {
                    s16x8 vf = *(const s16x8*)&Vs[(c * 16 + fr) * 64 + (((s * 64 + fq * 16) ^ sw) >> 1)];
                    o[c] = __builtin_amdgcn_mfma_f32_16x16x32_bf16(pf, vf, o[c], 0, 0, 0);
                }
            }
        }
    }
    #pragma unroll
    for (int c = 0; c < 8; c++)
        #pragma unroll
        for (int r = 0; r < 4; r++) {
            int rowq = qrow0 + fq * 4 + r;
            Ob[(size_t)rowq * 4096 + hq * 128 + c * 16 + fr] = f2bf(o[c][r] / li[r]);
        }
}

extern "C" void kernel_launch(void* const* d_in, const int* in_sizes, int n_in,
                              void* d_out, int out_size, void* d_ws, size_t ws_size,
                              hipStream_t stream) {
    const float* x  = (const float*)d_in[0];
    // d_in[1] = mask (unused; causal computed directly)
    const float* wq = (const float*)d_in[2];
    const float* wk = (const float*)d_in[3];
    const float* wv = (const float*)d_in[4];
    const float* wo = (const float*)d_in[5];
    float* out = (float*)d_out;

    char* w = (char*)d_ws;
    u16*   xb   = (u16*)(w);                    // 2048*4608 bf16       = 18,874,368
    u16*   wb   = (u16*)(w + 18874368);         // 8192*4608 bf16       = 75,497,472
    float* T32  = (float*)(w + 94371840);       // 2048*8192 f32        = 67,108,864
    u16*   Ob   = (u16*)(w + 94371840);         // overlaps T32 (dead by attn time)
    u16*   Qbuf = (u16*)(w + 161480704);        // 2048*4096 bf16       = 16,777,216
    u16*   Kbuf = (u16*)(w + 178257920);        // 2048*2048 bf16       =  8,388,608
    u16*   Vt   = (u16*)(w + 186646528);        // 2048*2048 bf16       =  8,388,608
    float* cosT = (float*)(w + 195035136);      // 2048*64 f32          =    524,288
    float* sinT = (float*)(w + 195559424);      // end 196,083,712

    // rope tables + input cast
    rope_table_kernel<<<512, 256, 0, stream>>>(cosT, sinT);
    cast_kernel<<<9216, 256, 0, stream>>>(x, xb);

    // fused QKV weights: wb rows [0,4096)=wq, [4096,6144)=wk, [6144,8192)=wv
    cast_kernel<<<18432, 256, 0, stream>>>(wq, wb);
    cast_kernel<<<9216, 256, 0, stream>>>(wk, wb + (size_t)4096 * 4608);
    cast_kernel<<<9216, 256, 0, stream>>>(wv, wb + (size_t)6144 * 4608);

    // fused QKV GEMM: (2048 x 8192, K=4608), 1024 blocks
    gemm_bt<<<1024, 256, 0, stream>>>(xb, wb, T32, 2048, 8192, 4608);

    // epilogues
    rope_q_kernel<<<16384, 256, 0, stream>>>(T32, Qbuf, cosT, sinT);
    rope_k_kernel<<<8192, 256, 0, stream>>>(T32, Kbuf, cosT, sinT);
    vtrans_kernel<<<4096, 256, 0, stream>>>(T32, Vt);

    // attention (T32 dead now; Ob aliases it)
    attn_kernel<<<1024, 256, 0, stream>>>(Qbuf, Kbuf, Vt, Ob);

    // out = attn @ wo^T (2048 x 4608, K=4096), split-K=2 atomic
    cast_kernel<<<18432, 256, 0, stream>>>(wo, wb);
    hipMemsetAsync(out, 0, (size_t)2048 * 4608 * 4, stream);
    gemm_bt_sk2<<<1152, 256, 0, stream>>>(Ob, wb, out, 2048, 4608, 4096);
}

// Round 4
// 555.626 us; speedup vs baseline: 1.5145x; 1.1719x over previous
//
#include <hip/hip_runtime.h>
#include <hip/hip_bf16.h>
#include <math.h>

typedef unsigned short u16;
typedef __attribute__((ext_vector_type(8))) short s16x8;
typedef __attribute__((ext_vector_type(4))) float f32x4;

#define SCALE 0.083333333333333329f   // 1/sqrt(144)
#define SOFTCAP_INV 0.02f

__device__ __forceinline__ u16 f2bf(float f) {
    unsigned u = __float_as_uint(f);
    unsigned r = 0x7fffu + ((u >> 16) & 1u);
    return (u16)((u + r) >> 16);
}

__device__ __forceinline__ float fast_tanh(float x) {
    float e = __expf(2.0f * x);
    return 1.0f - 2.0f / (e + 1.0f);
}

// ---------------- cast fp32 -> bf16 (vectorized) ----------------
__global__ __launch_bounds__(256) void cast_kernel(const float* __restrict__ in,
                                                   u16* __restrict__ out) {
    size_t i = ((size_t)blockIdx.x * 256 + threadIdx.x) * 4;
    float4 v = *(const float4*)(in + i);
    ushort4 o;
    o.x = f2bf(v.x); o.y = f2bf(v.y); o.z = f2bf(v.z); o.w = f2bf(v.w);
    *(ushort4*)(out + i) = o;
}

// ---------------- rope cos/sin table ----------------
__global__ __launch_bounds__(256) void rope_table_kernel(float* __restrict__ cosT,
                                                         float* __restrict__ sinT) {
    int idx = blockIdx.x * 256 + threadIdx.x;   // L*64
    int i = idx & 63, pos = idx >> 6;
    float inv = __expf(-((float)i / 64.0f) * 9.210340371976184f); // 10000^(-i/64)
    float ang = (float)pos * inv;
    cosT[idx] = cosf(ang);
    sinT[idx] = sinf(ang);
}

// ---------------- rope for Q from fused T32 [2048][8192], cols 0..4095 ----------------
__global__ __launch_bounds__(256) void rope_q_kernel(const float* __restrict__ T32,
                                                     u16* __restrict__ Qb,
                                                     const float* __restrict__ cosT,
                                                     const float* __restrict__ sinT) {
    int idx = blockIdx.x * 256 + threadIdx.x;   // L*32*64
    int i = idx & 63;
    int head = (idx >> 6) & 31;
    int pos = idx >> 11;
    size_t rbase = (size_t)pos * 8192 + head * 128 + i;
    float t1 = T32[rbase], t2 = T32[rbase + 64];
    float c = cosT[(pos << 6) + i], s = sinT[(pos << 6) + i];
    size_t wbase = (size_t)pos * 4096 + head * 128 + i;
    Qb[wbase]      = f2bf((t1 * c - t2 * s) * SCALE);
    Qb[wbase + 64] = f2bf((t2 * c + t1 * s) * SCALE);
}

// ---------------- rope for K from fused T32, cols 4096..6143 ----------------
__global__ __launch_bounds__(256) void rope_k_kernel(const float* __restrict__ T32,
                                                     u16* __restrict__ Kb,
                                                     const float* __restrict__ cosT,
                                                     const float* __restrict__ sinT) {
    int idx = blockIdx.x * 256 + threadIdx.x;   // L*16*64
    int i = idx & 63;
    int head = (idx >> 6) & 15;
    int pos = idx >> 10;
    size_t rbase = (size_t)pos * 8192 + 4096 + head * 128 + i;
    float t1 = T32[rbase], t2 = T32[rbase + 64];
    float c = cosT[(pos << 6) + i], s = sinT[(pos << 6) + i];
    size_t wbase = (size_t)pos * 2048 + head * 128 + i;
    Kb[wbase]      = f2bf(t1 * c - t2 * s);
    Kb[wbase + 64] = f2bf(t2 * c + t1 * s);
}

// ---------------- V transpose + cast from fused T32, cols 6144..8191 ----------------
__global__ __launch_bounds__(256) void vtrans_kernel(const float* __restrict__ T32,
                                                     u16* __restrict__ Vt) {
    __shared__ u16 tile[32][33];
    int bc = (blockIdx.x & 63) << 5;    // col within V block (0..2047)
    int bl = (blockIdx.x >> 6) << 5;    // row (l) tile
    int x = threadIdx.x & 31, y = threadIdx.x >> 5;
    #pragma unroll
    for (int yy = y; yy < 32; yy += 8)
        tile[yy][x] = f2bf(T32[(size_t)(bl + yy) * 8192 + 6144 + bc + x]);
    __syncthreads();
    #pragma unroll
    for (int yy = y; yy < 32; yy += 8)
        Vt[(size_t)(bc + yy) * 2048 + bl + x] = tile[x][yy];
}

// ============ 256x256 8-wave pipelined GEMM: C(MxN)=A(MxK)*B(NxK)^T ============
// BK=64. 512 thr = 8 waves (2Mx4N); per-wave 128x64 out (acc[8][4]).
// LDS 128KB = 2 bufs x (A 32KB + B 32KB). XOR swizzle (row&7)<<4 via pre-swizzled
// global source (linear global_load_lds dest) + swizzled ds_read.
// Pipeline: stage t+1 -> vmcnt(8) (keep t+1's 8 loads in flight) -> s_barrier ->
// ds_read+MFMA (tile t) -> s_barrier.  No vmcnt(0) until the last tile.
template<bool ATOMIC>
__device__ __forceinline__ void gemm256_core(const u16* __restrict__ A,
                                             const u16* __restrict__ B,
                                             float* __restrict__ C,
                                             int N, int K, int kbeg, int nt,
                                             int bm, int bn,
                                             u16 (&lds)[2][2][16384]) {
    int t = threadIdx.x;
    int lane = t & 63, wave = t >> 6;
    int wm = wave >> 2, wn = wave & 3;
    int fr = lane & 15, fq = lane >> 4;
    int sw = (fr & 7) << 4;

    // staging: load l covers LDS rows l*64 + wave*8 + (lane>>3), 128B rows
    int srow = wave * 8 + (lane >> 3);
    int scb = ((lane & 7) * 16) ^ (((lane >> 3) & 7) << 4);   // pre-swizzled src col byte
    const u16* aSrc = A + (size_t)(bm * 256 + srow) * K + kbeg + (scb >> 1);
    const u16* bSrc = B + (size_t)(bn * 256 + srow) * K + kbeg + (scb >> 1);
    int ldsoff = wave * 512;   // elements

    f32x4 acc[8][4];
    #pragma unroll
    for (int m = 0; m < 8; m++)
        #pragma unroll
        for (int n = 0; n < 4; n++)
            acc[m][n] = (f32x4){0.f, 0.f, 0.f, 0.f};

    // prologue: stage tile 0 into buf 0 (8 loads per wave in flight)
    #pragma unroll
    for (int l = 0; l < 4; ++l) {
        __builtin_amdgcn_global_load_lds(
            (const __attribute__((address_space(1))) unsigned int*)(aSrc + (size_t)l * 64 * K),
            (__attribute__((address_space(3))) unsigned int*)(&lds[0][0][l * 4096 + ldsoff]), 16, 0, 0);
        __builtin_amdgcn_global_load_lds(
            (const __attribute__((address_space(1))) unsigned int*)(bSrc + (size_t)l * 64 * K),
            (__attribute__((address_space(3))) unsigned int*)(&lds[0][1][l * 4096 + ldsoff]), 16, 0, 0);
    }

    for (int it = 0; it < nt; ++it) {
        int cur = it & 1;
        if (it + 1 < nt) {
            const u16* aN = aSrc + (size_t)(it + 1) * 64;
            const u16* bN = bSrc + (size_t)(it + 1) * 64;
            #pragma unroll
            for (int l = 0; l < 4; ++l) {
                __builtin_amdgcn_global_load_lds(
                    (const __attribute__((address_space(1))) unsigned int*)(aN + (size_t)l * 64 * K),
                    (__attribute__((address_space(3))) unsigned int*)(&lds[cur ^ 1][0][l * 4096 + ldsoff]), 16, 0, 0);
                __builtin_amdgcn_global_load_lds(
                    (const __attribute__((address_space(1))) unsigned int*)(bN + (size_t)l * 64 * K),
                    (__attribute__((address_space(3))) unsigned int*)(&lds[cur ^ 1][1][l * 4096 + ldsoff]), 16, 0, 0);
            }
            asm volatile("s_waitcnt vmcnt(8)" ::: "memory");   // tile t landed; t+1 in flight
        } else {
            asm volatile("s_waitcnt vmcnt(0)" ::: "memory");   // last tile: drain
        }
        __builtin_amdgcn_s_barrier();
        asm volatile("" ::: "memory");
        __builtin_amdgcn_sched_barrier(0);

        const char* Ab = (const char*)&lds[cur][0][0];
        const char* Bb = (const char*)&lds[cur][1][0];
        s16x8 bfr[4][2];
        #pragma unroll
        for (int n = 0; n < 4; ++n)
            #pragma unroll
            for (int kk = 0; kk < 2; ++kk) {
                int row = wn * 64 + n * 16 + fr;
                int cb = (kk * 64 + fq * 16) ^ sw;
                bfr[n][kk] = *(const s16x8*)(Bb + row * 128 + cb);
            }
        #pragma unroll
        for (int mh = 0; mh < 2; ++mh) {
            s16x8 afr[4][2];
            #pragma unroll
            for (int mm = 0; mm < 4; ++mm)
                #pragma unroll
                for (int kk = 0; kk < 2; ++kk) {
                    int row = wm * 128 + (mh * 4 + mm) * 16 + fr;
                    int cb = (kk * 64 + fq * 16) ^ sw;
                    afr[mm][kk] = *(const s16x8*)(Ab + row * 128 + cb);
                }
            __builtin_amdgcn_s_setprio(1);
            #pragma unroll
            for (int mm = 0; mm < 4; ++mm)
                #pragma unroll
                for (int n = 0; n < 4; ++n)
                    #pragma unroll
                    for (int kk = 0; kk < 2; ++kk)
                        acc[mh * 4 + mm][n] = __builtin_amdgcn_mfma_f32_16x16x32_bf16(
                            afr[mm][kk], bfr[n][kk], acc[mh * 4 + mm][n], 0, 0, 0);
            __builtin_amdgcn_s_setprio(0);
        }
        __builtin_amdgcn_sched_barrier(0);
        asm volatile("" ::: "memory");
        __builtin_amdgcn_s_barrier();   // all waves done reading buf[cur]
    }

    #pragma unroll
    for (int m = 0; m < 8; ++m) {
        int row = bm * 256 + wm * 128 + m * 16 + fq * 4;
        #pragma unroll
        for (int n = 0; n < 4; ++n) {
            int col = bn * 256 + wn * 64 + n * 16 + fr;
            #pragma unroll
            for (int r = 0; r < 4; ++r) {
                if (ATOMIC) atomicAdd(&C[(size_t)(row + r) * N + col], acc[m][n][r]);
                else        C[(size_t)(row + r) * N + col] = acc[m][n][r];
            }
        }
    }
}

// QKV GEMM: M=2048,N=8192,K=4608. grid 256. Column-stripe per XCD:
// XCD x owns bn in [x*4, x*4+4) x all 8 bm -> per-XCD fetch = A(full) + B/8.
__global__ __launch_bounds__(512) void gemm256_qkv(const u16* __restrict__ A,
                                                   const u16* __restrict__ B,
                                                   float* __restrict__ C, int K) {
    __shared__ u16 lds[2][2][16384];
    int bid = blockIdx.x;
    int x = bid & 7, j = bid >> 3;
    int bn = x * 4 + (j & 3);
    int bm = j >> 2;
    gemm256_core<false>(A, B, C, 8192, K, 0, K >> 6, bm, bn, lds);
}

// out-proj GEMM: M=2048,N=4608,K=4096, split-K=2 (atomic). grid 288.
__global__ __launch_bounds__(512) void gemm256_out(const u16* __restrict__ A,
                                                   const u16* __restrict__ B,
                                                   float* __restrict__ C, int K) {
    __shared__ u16 lds[2][2][16384];
    int bid = blockIdx.x;
    int sk = bid & 1;
    int tid = bid >> 1;            // 0..143
    int bm = tid & 7;              // column-major: consecutive tiles share B panel
    int bn = tid >> 3;             // 0..17
    gemm256_core<true>(A, B, C, 4608, K, sk * (K >> 1), K >> 7, bm, bn, lds);
}

// ---------------- flash attention: 4 waves/block, LDS-staged K/V ----------------
__global__ __launch_bounds__(256) void attn_kernel(const u16* __restrict__ Qb,
                                                   const u16* __restrict__ Kb,
                                                   const u16* __restrict__ Vt,
                                                   u16* __restrict__ Ob) {
    __shared__ u16 Ks[64 * 128];    // 16 KB, swizzled
    __shared__ u16 Vs[128 * 64];    // 16 KB, swizzled
    __shared__ u16 Pst[4 * 1024];   // 2 KB per wave

    int bid = blockIdx.x;
    int hq = bid & 31;
    int qb = 31 - (bid >> 5);       // heavy blocks first
    int g = hq >> 1;
    int t = threadIdx.x;
    int lane = t & 63, wave = t >> 6;
    int fr = lane & 15, fq = lane >> 4;
    int sw = (fr & 7) << 4;
    int qrow0 = qb * 64 + wave * 16;
    u16* Pw = &Pst[wave * 1024];

    s16x8 qf[4];
    #pragma unroll
    for (int s = 0; s < 4; s++)
        qf[s] = *(const s16x8*)&Qb[(size_t)(qrow0 + fr) * 4096 + hq * 128 + s * 32 + fq * 8];

    f32x4 o[8];
    #pragma unroll
    for (int c = 0; c < 8; c++) o[c] = (f32x4){0.f, 0.f, 0.f, 0.f};
    float mi[4] = {-INFINITY, -INFINITY, -INFINITY, -INFINITY};
    float li[4] = {0.f, 0.f, 0.f, 0.f};

    int w4 = wave * 4;
    int nT = qb + 1;
    for (int kt = 0; kt < nT; kt++) {
        int kv0 = kt << 6;
        __syncthreads();
        #pragma unroll
        for (int i = 0; i < 4; i++) {
            int li_ = w4 + i;
            int rk = li_ * 4 + (lane >> 4);
            int cbk = ((lane & 15) * 16) ^ ((rk & 7) << 4);
            const u16* srcK = Kb + (size_t)(kv0 + rk) * 2048 + g * 128 + (cbk >> 1);
            __builtin_amdgcn_global_load_lds(
                (const __attribute__((address_space(1))) unsigned int*)srcK,
                (__attribute__((address_space(3))) unsigned int*)(Ks + li_ * 512), 16, 0, 0);
            int rv = li_ * 8 + (lane >> 3);
            int cbv = ((lane & 7) * 16) ^ ((rv & 7) << 4);
            const u16* srcV = Vt + (size_t)(g * 128 + rv) * 2048 + kv0 + (cbv >> 1);
            __builtin_amdgcn_global_load_lds(
                (const __attribute__((address_space(1))) unsigned int*)srcV,
                (__attribute__((address_space(3))) unsigned int*)(Vs + li_ * 512), 16, 0, 0);
        }
        __syncthreads();

        if (kv0 <= qrow0 + 15) {
            f32x4 sf[4];
            #pragma unroll
            for (int j = 0; j < 4; j++) sf[j] = (f32x4){0.f, 0.f, 0.f, 0.f};
            #pragma unroll
            for (int j = 0; j < 4; j++)
                #pragma unroll
                for (int s = 0; s < 4; s++) {
                    s16x8 kf = *(const s16x8*)&Ks[(j * 16 + fr) * 128 + (((s * 64 + fq * 16) ^ sw) >> 1)];
                    sf[j] = __builtin_amdgcn_mfma_f32_16x16x32_bf16(qf[s], kf, sf[j], 0, 0, 0);
                }
            float pmax[4] = {-INFINITY, -INFINITY, -INFINITY, -INFINITY};
            #pragma unroll
            for (int j = 0; j < 4; j++)
                #pragma unroll
                for (int r = 0; r < 4; r++) {
                    float sc = 50.f * fast_tanh(sf[j][r] * SOFTCAP_INV);
                    int colk = kv0 + j * 16 + fr;
                    int rowq = qrow0 + fq * 4 + r;
                    sc = (colk > rowq) ? -INFINITY : sc;
                    sf[j][r] = sc;
                    pmax[r] = fmaxf(pmax[r], sc);
                }
            #pragma unroll
            for (int d = 1; d < 16; d <<= 1)
                #pragma unroll
                for (int r = 0; r < 4; r++)
                    pmax[r] = fmaxf(pmax[r], __shfl_xor(pmax[r], d));
            float al[4], psum[4] = {0.f, 0.f, 0.f, 0.f};
            #pragma unroll
            for (int r = 0; r < 4; r++) {
                float mn = fmaxf(mi[r], pmax[r]);
                al[r] = __expf(mi[r] - mn);
                mi[r] = mn;
            }
            #pragma unroll
            for (int j = 0; j < 4; j++)
                #pragma unroll
                for (int r = 0; r < 4; r++) {
                    float p = __expf(sf[j][r] - mi[r]);
                    sf[j][r] = p;
                    psum[r] += p;
                }
            #pragma unroll
            for (int d = 1; d < 16; d <<= 1)
                #pragma unroll
                for (int r = 0; r < 4; r++)
                    psum[r] += __shfl_xor(psum[r], d);
            #pragma unroll
            for (int r = 0; r < 4; r++)
                li[r] = li[r] * al[r] + psum[r];
            #pragma unroll
            for (int c = 0; c < 8; c++)
                #pragma unroll
                for (int r = 0; r < 4; r++)
                    o[c][r] *= al[r];
            #pragma unroll
            for (int j = 0; j < 4; j++)
                #pragma unroll
                for (int r = 0; r < 4; r++) {
                    int row = fq * 4 + r, col = j * 16 + fr;
                    int byteoff = (row * 128 + col * 2) ^ ((row & 7) << 4);
                    *(u16*)((char*)Pw + byteoff) = f2bf(sf[j][r]);
                }
            #pragma unroll
            for (int s = 0; s < 2; s++) {
                int rbyte = (fr * 128 + s * 64 + fq * 16) ^ sw;
                s16x8 pf = *(const s16x8*)((const char*)Pw + rbyte);
                #pragma unroll
                for (int c = 0; c < 8; c++) {
                    s16x8 vf = *(const s16x8*)&Vs[(c * 16 + fr) * 64 + (((s * 64 + fq * 16) ^ sw) >> 1)];
                    o[c] = __builtin_amdgcn_mfma_f32_16x16x32_bf16(pf, vf, o[c], 0, 0, 0);
                }
            }
        }
    }
    #pragma unroll
    for (int c = 0; c < 8; c++)
        #pragma unroll
        for (int r = 0; r < 4; r++) {
            int rowq = qrow0 + fq * 4 + r;
            Ob[(size_t)rowq * 4096 + hq * 128 + c * 16 + fr] = f2bf(o[c][r] / li[r]);
        }
}

extern "C" void kernel_launch(void* const* d_in, const int* in_sizes, int n_in,
                              void* d_out, int out_size, void* d_ws, size_t ws_size,
                              hipStream_t stream) {
    const float* x  = (const float*)d_in[0];
    // d_in[1] = mask (unused; causal computed directly)
    const float* wq = (const float*)d_in[2];
    const float* wk = (const float*)d_in[3];
    const float* wv = (const float*)d_in[4];
    const float* wo = (const float*)d_in[5];
    float* out = (float*)d_out;

    char* w = (char*)d_ws;
    u16*   xb   = (u16*)(w);                    // 2048*4608 bf16       = 18,874,368
    u16*   wb   = (u16*)(w + 18874368);         // 8192*4608 bf16       = 75,497,472
    float* T32  = (float*)(w + 94371840);       // 2048*8192 f32        = 67,108,864
    u16*   Ob   = (u16*)(w + 94371840);         // overlaps T32 (dead by attn time)
    u16*   Qbuf = (u16*)(w + 161480704);        // 2048*4096 bf16       = 16,777,216
    u16*   Kbuf = (u16*)(w + 178257920);        // 2048*2048 bf16       =  8,388,608
    u16*   Vt   = (u16*)(w + 186646528);        // 2048*2048 bf16       =  8,388,608
    float* cosT = (float*)(w + 195035136);      // 2048*64 f32          =    524,288
    float* sinT = (float*)(w + 195559424);      // end 196,083,712

    // rope tables + input cast
    rope_table_kernel<<<512, 256, 0, stream>>>(cosT, sinT);
    cast_kernel<<<9216, 256, 0, stream>>>(x, xb);

    // fused QKV weights: wb rows [0,4096)=wq, [4096,6144)=wk, [6144,8192)=wv
    cast_kernel<<<18432, 256, 0, stream>>>(wq, wb);
    cast_kernel<<<9216, 256, 0, stream>>>(wk, wb + (size_t)4096 * 4608);
    cast_kernel<<<9216, 256, 0, stream>>>(wv, wb + (size_t)6144 * 4608);

    // fused QKV GEMM: (2048 x 8192, K=4608), 256 blocks x 512 thr
    gemm256_qkv<<<256, 512, 0, stream>>>(xb, wb, T32, 4608);

    // epilogues
    rope_q_kernel<<<16384, 256, 0, stream>>>(T32, Qbuf, cosT, sinT);
    rope_k_kernel<<<8192, 256, 0, stream>>>(T32, Kbuf, cosT, sinT);
    vtrans_kernel<<<4096, 256, 0, stream>>>(T32, Vt);

    // attention (T32 dead now; Ob aliases it)
    attn_kernel<<<1024, 256, 0, stream>>>(Qbuf, Kbuf, Vt, Ob);

    // out = attn @ wo^T (2048 x 4608, K=4096), split-K=2 atomic
    cast_kernel<<<18432, 256, 0, stream>>>(wo, wb);
    hipMemsetAsync(out, 0, (size_t)2048 * 4608 * 4, stream);
    gemm256_out<<<288, 512, 0, stream>>>(Ob, wb, out, 4096);
}